// Round 13
// baseline (261.235 us; speedup 1.0000x reference)
//
#include <hip/hip_runtime.h>
#include <cstdint>
#include <math.h>

// Canny_1116691497316: per-channel Canny edges, out = x[:,indices] * tf
// x: (1,64,512,512) f32, indices: (32,) int32, out: (1,32,512,512) f32
//
// Round 13: f32 predictor pipeline; boundary-margin pixels appended to a
// global flag list (in d_out, dead until mul); separate f64 fixup kernel
// rechecks them (exact rounds-7-11 f64 value chains, absmax 0.0) and patches
// the bitmaps. No f64 / no scratch in the hot kernel (round-12 lesson).
// Pipeline: memset(counter) -> canny_fused -> fixup -> hyst_iterate -> mul.

constexpr int HH = 512;
constexpr int WW = 512;
constexpr int HW = HH * WW;          // 262144 px per channel
constexpr int KCH = 32;              // selected channels
constexpr int WORDS = HW / 32;       // 8192 uint32 words per bitmap per channel

constexpr int TD = 32;               // tile dim (32x32 output px)
constexpr int NT = HH / TD;          // 16 tiles per side, 256 per channel

// padded LDS strides (break stride-mod-32 bank aliasing)
constexpr int IN_P = 41;             // in tile 40x40, stride 41
constexpr int VP_P = 41;             // vp tile 36x40, stride 41
constexpr int BL_P = 37;             // bl tile 36x36, stride 37
constexpr int SQ_P = 35;             // sq tile 34x34, stride 35

constexpr unsigned int LISTCAP = 262144;   // flag-list capacity (1 MB in d_out)

// f64 gaussian weights, exact value chain of the reference
constexpr double E2 = 0.13533528323661269189;  // exp(-2.0)
constexpr double E1 = 0.60653065971263342360;  // exp(-0.5)
constexpr double GS = ((((E2 + E1) + 1.0) + E1) + E2);
constexpr double GW0 = E2 / GS, GW1 = E1 / GS, GW2 = 1.0 / GS;

constexpr double T1 = 0.4142135623730950488;   // tan(22.5deg)
constexpr double T2 = 2.4142135623730950488;   // tan(67.5deg)
constexpr double SQ_HI = 0.2 * 0.2;
constexpr double SQ_LO = 0.1 * 0.1;

__device__ __forceinline__ int reflect_idx(int v) {
    return v < 0 ? -v : (v > 511 ? 1022 - v : v);
}
__device__ __forceinline__ int clampi(int v) {
    return v < 0 ? 0 : (v > 511 ? 511 : v);
}

// axis a in {0..3}: NMS neighbor pair, == rint(atan2(gy,gx)*(180/pi)/45) mod 4
__device__ const int AY1[4] = {0, 1, 1, 1};
__device__ const int AX1[4] = {1, 1, 0, -1};

// ---------------- Kernel 1: fused f32 blur + sobel + mag^2 + NMS + flag append ----------------
// One 256-thread block per 32x32 output tile. LDS (18,960 B -> 8 blocks/CU):
//   [0, 6560):      in f32 [40 x stride 41]
//   [6560, 12464):  vp f32 [36 x stride 41] -> sq f32 [34 x stride 35] overlay
//   [12464, 17792): bl f32 [36 x stride 37]
//   [17792, 18816): ax u8 [32*32] (bit2 = axis-borderline flag)
//   [18816, 18952): RU/RD/CL/CR u8[34] x4
__global__ __launch_bounds__(256) void canny_fused(const float* __restrict__ x,
                                                   const int* __restrict__ idx,
                                                   unsigned int* __restrict__ weakb,
                                                   unsigned int* __restrict__ strongb,
                                                   unsigned int* __restrict__ fcount,
                                                   unsigned int* __restrict__ flist) {
    __shared__ __align__(16) char lds[18960];
    float* in_s = (float*)lds;                             // [40*41]
    float* vp_s = (float*)(lds + 6560);                    // [36*41]
    float* sq_s = (float*)(lds + 6560);                    // [34*35] overlay (vp dead)
    float* bl_s = (float*)(lds + 12464);                   // [36*37]
    unsigned char* ax_s = (unsigned char*)(lds + 17792);   // [32*32]
    unsigned char* RUm = (unsigned char*)(lds + 18816);    // [34]
    unsigned char* RDm = RUm + 34;
    unsigned char* CLm = RUm + 68;
    unsigned char* CRm = RUm + 102;

    int tile = blockIdx.x;
    int k = tile >> 8;                 // 256 tiles per channel
    int t = tile & 255;
    int ty0 = (t >> 4) * TD;
    int tx0 = (t & 15) * TD;
    int tid = threadIdx.x;

    int ch = idx[k];
    const float* img = x + (size_t)ch * HW;

    // ---- clamp tables (parallel with load; single barrier covers both) ----
    if (tid < 34) {
        int u = ty0 - 1 + tid;
        RUm[tid] = (unsigned char)(clampi(u - 1) - (ty0 - 2));
        RDm[tid] = (unsigned char)(clampi(u + 1) - (ty0 - 2));
    } else if (tid >= 64 && tid < 98) {
        int bm = tid - 64;
        int v = tx0 - 1 + bm;
        CLm[bm] = (unsigned char)(clampi(v - 1) - (tx0 - 2));
        CRm[bm] = (unsigned char)(clampi(v + 1) - (tx0 - 2));
    }

    // ---- load input tile 40x40, inline reflect ----
    {
        int a = tid / 40, b = tid - (tid / 40) * 40;
        while (a < 40) {
            in_s[a * IN_P + b] = img[reflect_idx(ty0 - 4 + a) * WW + reflect_idx(tx0 - 4 + b)];
            b += 16; a += 6;
            if (b >= 40) { b -= 40; a += 1; }
        }
    }
    __syncthreads();

    const float gf0 = (float)GW0, gf1 = (float)GW1, gf2 = (float)GW2;

    // ---- vertical blur (f32): sliding window, lane-major columns ----
    if (tid < 240) {
        int rg = tid / 40;
        int b = tid - 40 * rg;
        int a0 = 6 * rg;
        float w[10];
        #pragma unroll
        for (int j = 0; j < 10; j++) w[j] = in_s[(a0 + j) * IN_P + b];
        #pragma unroll
        for (int i = 0; i < 6; i++) {
            float acc = gf0 * w[i];
            acc += gf1 * w[i + 1];
            acc += gf2 * w[i + 2];
            acc += gf1 * w[i + 3];
            acc += gf0 * w[i + 4];
            vp_s[(a0 + i) * VP_P + b] = acc;
        }
    }
    __syncthreads();

    // ---- horizontal blur (f32): per-cell linear ----
    {
        int a = tid / 36, b = tid - 36 * (tid / 36);
        while (a < 36) {
            const float* vr = vp_s + a * VP_P + b;
            float acc = gf0 * vr[0];
            acc += gf1 * vr[1];
            acc += gf2 * vr[2];
            acc += gf1 * vr[3];
            acc += gf0 * vr[4];
            bl_s[a * BL_P + b] = acc;
            b += 4; a += 7;
            if (b >= 36) { b -= 36; a += 1; }
        }
    }
    __syncthreads();   // fences vp reads before sq overlay writes

    // ---- mag^2 + axis (f32) with axis-borderline flag ----
    const float T1f = (float)T1, T2f = (float)T2;
    {
        int am = tid / 34, bm = tid - 34 * (tid / 34);
        while (am < 34) {
            int ru = RUm[am], r0 = am + 1, rd = RDm[am];
            int cl = CLm[bm], c0 = bm + 1, cr = CRm[bm];
            float v00 = bl_s[ru * BL_P + cl], v01 = bl_s[ru * BL_P + c0], v02 = bl_s[ru * BL_P + cr];
            float v10 = bl_s[r0 * BL_P + cl],                              v12 = bl_s[r0 * BL_P + cr];
            float v20 = bl_s[rd * BL_P + cl], v21 = bl_s[rd * BL_P + c0], v22 = bl_s[rd * BL_P + cr];
            float gxv = ((((-v00 + v02) + (-2.0f * v10)) + (2.0f * v12)) + (-v20)) + v22;
            float gyv = ((((-v00 + (-2.0f * v01)) + (-v02)) + v20) + (2.0f * v21)) + v22;
            sq_s[am * SQ_P + bm] = (gxv * gxv + gyv * gyv) + 1e-6f;

            if (am >= 1 && am <= TD && bm >= 1 && bm <= TD) {
                float axf = fabsf(gxv), ayf = fabsf(gyv);
                int axis;
                if (ayf < T1f * axf) axis = 0;
                else if (ayf > T2f * axf) axis = 2;
                else {
                    float gxf = (gyv < 0.0f) ? -gxv : gxv;
                    axis = (gxf > 0.0f) ? 1 : 3;
                }
                float mrg = 3e-4f * (axf + ayf);
                bool aflag = (fabsf(ayf - T1f * axf) <= mrg) ||
                             (fabsf(ayf - T2f * axf) <= mrg) ||
                             (axf <= mrg) || (ayf <= mrg);
                ax_s[(am - 1) * TD + (bm - 1)] = (unsigned char)(axis | (aflag ? 4 : 0));
            }
            bm += 18; am += 7;
            if (bm >= 34) { bm -= 34; am += 1; }
        }
    }
    __syncthreads();

    // ---- NMS + thresholds (f32); flagged pixels appended for f64 fixup ----
    #pragma unroll
    for (int q4 = 0; q4 < TD * TD / 256; q4++) {
        int l = q4 * 256 + tid;
        int oy = l >> 5, ox = l & 31;
        int gy = ty0 + oy, gx = tx0 + ox;

        unsigned char av = ax_s[oy * TD + ox];
        int axis = av & 3;
        bool flag = (av & 4) != 0;
        int dy = AY1[axis], dx = AX1[axis];
        float s = sq_s[(oy + 1) * SQ_P + (ox + 1)];

        int y1 = gy + dy, x1 = gx + dx;
        int y2 = gy - dy, x2 = gx - dx;
        bool in1 = (y1 >= 0) && (y1 < HH) && (x1 >= 0) && (x1 < WW);
        bool in2 = (y2 >= 0) && (y2 < HH) && (x2 >= 0) && (x2 < WW);
        float s1 = in1 ? sq_s[(oy + 1 + dy) * SQ_P + (ox + 1 + dx)] : 0.0f;
        float s2 = in2 ? sq_s[(oy + 1 - dy) * SQ_P + (ox + 1 - dx)] : 0.0f;
        bool keep = (s > s1) && (s > s2);
        bool strong = keep && (s > 0.04f);
        bool weak = keep && (s > 0.01f) && !strong;

        const float e = 3e-4f;
        flag = flag || (in1 && fabsf(s - s1) <= e * (s + s1));
        flag = flag || (in2 && fabsf(s - s2) <= e * (s + s2));
        flag = flag || (fabsf(s - 0.04f) <= e * (s + 0.04f));
        flag = flag || (fabsf(s - 0.01f) <= e * (s + 0.01f));

        if (__builtin_expect((int)flag, 0)) {
            unsigned int pos = atomicAdd(fcount, 1u);
            if (pos < LISTCAP)
                flist[pos] = ((unsigned int)k << 18) | ((unsigned int)gy << 9) | (unsigned int)gx;
        }

        unsigned long long wb = __ballot(weak);
        unsigned long long sb = __ballot(strong);
        if ((tid & 31) == 0) {
            unsigned int ww = (tid & 32) ? (unsigned int)(wb >> 32) : (unsigned int)wb;
            unsigned int sw = (tid & 32) ? (unsigned int)(sb >> 32) : (unsigned int)sb;
            size_t w32 = ((size_t)k * HW + (size_t)gy * WW + tx0) >> 5;
            weakb[w32] = ww;
            strongb[w32] = sw;
        }
    }
}

// ---------------- Kernel 2: f64 fixup of flagged pixels ----------------
// Reproduces the rounds-7-11 f64 value chains exactly, reading x directly.
__device__ double blur64g(const float* __restrict__ img, int iy, int ix) {
    const double G[5] = {GW0, GW1, GW2, GW1, GW0};
    double acc = 0.0;
    #pragma unroll
    for (int i = 0; i < 5; i++) {
        double col = 0.0;
        #pragma unroll
        for (int j = 0; j < 5; j++)
            col += G[j] * (double)img[reflect_idx(iy - 2 + j) * WW + reflect_idx(ix - 2 + i)];
        acc += G[i] * col;
    }
    return acc;
}
__device__ void sobel64g(const float* __restrict__ img, int py, int px,
                         double& gxv, double& gyv) {
    int ru = clampi(py - 1), r0 = py, rd = clampi(py + 1);
    int cl = clampi(px - 1), c0 = px, cr = clampi(px + 1);
    double v00 = blur64g(img, ru, cl), v01 = blur64g(img, ru, c0), v02 = blur64g(img, ru, cr);
    double v10 = blur64g(img, r0, cl),                              v12 = blur64g(img, r0, cr);
    double v20 = blur64g(img, rd, cl), v21 = blur64g(img, rd, c0), v22 = blur64g(img, rd, cr);
    gxv = ((((-v00 + v02) + (-2.0 * v10)) + (2.0 * v12)) + (-v20)) + v22;
    gyv = ((((-v00 + (-2.0 * v01)) + (-v02)) + v20) + (2.0 * v21)) + v22;
}

__global__ __launch_bounds__(256) void fixup_kernel(const float* __restrict__ x,
                                                    const int* __restrict__ idx,
                                                    const unsigned int* __restrict__ fcount,
                                                    const unsigned int* __restrict__ flist,
                                                    unsigned int* __restrict__ weakb,
                                                    unsigned int* __restrict__ strongb) {
    unsigned int n = *fcount;
    if (n > LISTCAP) n = LISTCAP;
    unsigned int i = blockIdx.x * 256 + threadIdx.x;
    if (i >= n) return;

    unsigned int en = flist[i];
    int k = (int)(en >> 18);
    int gy = (int)((en >> 9) & 511);
    int gx = (int)(en & 511);
    const float* img = x + (size_t)idx[k] * HW;

    double gxc, gyc;
    sobel64g(img, gy, gx, gxc, gyc);
    double s = (gxc * gxc + gyc * gyc) + 1e-6;

    double ax = fabs(gxc), ay = fabs(gyc);
    int axis;
    if (ay < T1 * ax) axis = 0;
    else if (ay > T2 * ax) axis = 2;
    else {
        double gxf = (gyc < 0.0) ? -gxc : gxc;
        axis = (gxf > 0.0) ? 1 : 3;
    }
    int dy = AY1[axis], dx = AX1[axis];

    double s1 = 0.0, s2 = 0.0, tx, ty;
    int y1 = gy + dy, x1 = gx + dx, y2 = gy - dy, x2 = gx - dx;
    if (y1 >= 0 && y1 < HH && x1 >= 0 && x1 < WW) {
        sobel64g(img, y1, x1, tx, ty);
        s1 = (tx * tx + ty * ty) + 1e-6;
    }
    if (y2 >= 0 && y2 < HH && x2 >= 0 && x2 < WW) {
        sobel64g(img, y2, x2, tx, ty);
        s2 = (tx * tx + ty * ty) + 1e-6;
    }
    bool keep = (s > s1) && (s > s2);
    bool strong = keep && (s > SQ_HI);
    bool weak = keep && (s > SQ_LO) && !strong;

    size_t p = (size_t)k * HW + (size_t)gy * WW + gx;
    unsigned int m = 1u << (p & 31);
    size_t w = p >> 5;
    if (weak) atomicOr(&weakb[w], m); else atomicAnd(&weakb[w], ~m);
    if (strong) atomicOr(&strongb[w], m); else atomicAnd(&strongb[w], ~m);
}

// ---------------- Kernel 3: hysteresis closure on bitmaps ----------------
__global__ __launch_bounds__(1024) void hyst_iterate(const unsigned int* __restrict__ weakb,
                                                     unsigned int* __restrict__ strongb) {
    int k = blockIdx.x;
    __shared__ unsigned int Sm[WORDS];
    __shared__ int s_changed;
    int tid = threadIdx.x;

    const unsigned int* wsrc = weakb + (size_t)k * WORDS;
    unsigned int* ssrc = strongb + (size_t)k * WORDS;

    if (tid == 0) s_changed = 0;
    for (int i = tid; i < WORDS; i += 1024) Sm[i] = ssrc[i];
    unsigned int wreg[8];
    #pragma unroll
    for (int q = 0; q < 8; q++) wreg[q] = wsrc[tid * 8 + q];
    __syncthreads();

    for (;;) {
        int loc = 0;
        #pragma unroll
        for (int q = 0; q < 8; q++) {
            int w = tid * 8 + q;
            unsigned int s = Sm[w];
            unsigned int wk = wreg[q] & ~s;
            if (!wk) continue;
            int j = w & 15;
            unsigned int L = j ? Sm[w - 1] : 0u;
            unsigned int R = (j < 15) ? Sm[w + 1] : 0u;
            unsigned int D = (s << 1) | (L >> 31) | (s >> 1) | (R << 31);
            if (w >= 16) {
                unsigned int cu = Sm[w - 16];
                unsigned int Lu = j ? Sm[w - 17] : 0u;
                unsigned int Ru = (j < 15) ? Sm[w - 15] : 0u;
                D |= cu | (cu << 1) | (Lu >> 31) | (cu >> 1) | (Ru << 31);
            }
            if (w < WORDS - 16) {
                unsigned int cd = Sm[w + 16];
                unsigned int Ld = j ? Sm[w + 15] : 0u;
                unsigned int Rd = (j < 15) ? Sm[w + 17] : 0u;
                D |= cd | (cd << 1) | (Ld >> 31) | (cd >> 1) | (Rd << 31);
            }
            unsigned int promoted = wk & D;
            if (promoted) { Sm[w] = s | promoted; loc = 1; }
        }
        if (loc) s_changed = 1;
        __syncthreads();
        int chg = s_changed;
        __syncthreads();
        if (!chg) break;
        if (tid == 0) s_changed = 0;
        __syncthreads();
    }

    for (int i = tid; i < WORDS; i += 1024) ssrc[i] = Sm[i];
}

// ---------------- Kernel 4: out = x[:,indices] * tf, full grid, float4 ----------------
__global__ void mul_kernel(const float* __restrict__ x,
                           const int* __restrict__ idx,
                           const unsigned int* __restrict__ weakb,
                           const unsigned int* __restrict__ strongb,
                           float* __restrict__ out) {
    int gid = blockIdx.x * blockDim.x + threadIdx.x;
    int p = gid * 4;
    if (p >= KCH * HW) return;
    int k = p >> 18;
    int r = p & (HW - 1);
    int ch = idx[k];

    unsigned int sw = strongb[p >> 5];
    unsigned int ww = weakb[p >> 5];
    int b0 = p & 31;

    const float4 xv = *reinterpret_cast<const float4*>(x + (size_t)ch * HW + r);
    float t[4];
    #pragma unroll
    for (int i = 0; i < 4; i++) {
        int b = b0 + i;
        t[i] = ((sw >> b) & 1u) ? 1.0f : (((ww >> b) & 1u) ? 0.5f : 0.0f);
    }
    float4 o;
    o.x = xv.x * t[0];
    o.y = xv.y * t[1];
    o.z = xv.z * t[2];
    o.w = xv.w * t[3];
    *reinterpret_cast<float4*>(out + (size_t)p) = o;
}

extern "C" void kernel_launch(void* const* d_in, const int* in_sizes, int n_in,
                              void* d_out, int out_size, void* d_ws, size_t ws_size,
                              hipStream_t stream) {
    const float* x = (const float*)d_in[0];
    // d_in[1] = params (always 1 here; params==0 changes output shape, impossible
    // given out_size)
    const int* idx = (const int*)d_in[2];
    float* out = (float*)d_out;

    char* ws = (char*)d_ws;
    unsigned int* weakb = (unsigned int*)ws;                 // 1 MB
    unsigned int* strongb = (unsigned int*)(ws + 1048576);   // 1 MB

    // flag counter + list live in d_out (dead until mul_kernel overwrites it)
    unsigned int* fcount = (unsigned int*)d_out;
    unsigned int* flist = ((unsigned int*)d_out) + 64;       // 1 MB list region

    hipMemsetAsync(fcount, 0, 4, stream);

    int ntiles = KCH * NT * NT;  // 8192
    canny_fused<<<ntiles, 256, 0, stream>>>(x, idx, weakb, strongb, fcount, flist);
    fixup_kernel<<<LISTCAP / 256, 256, 0, stream>>>(x, idx, fcount, flist, weakb, strongb);
    hyst_iterate<<<KCH, 1024, 0, stream>>>(weakb, strongb);
    mul_kernel<<<(KCH * HW / 4) / 256, 256, 0, stream>>>(x, idx, weakb, strongb, out);
}

// Round 14
// 130.447 us; speedup vs baseline: 2.0026x; 2.0026x over previous
//
#include <hip/hip_runtime.h>
#include <cstdint>
#include <math.h>

// Canny_1116691497316: per-channel Canny edges, out = x[:,indices] * tf
// x: (1,64,512,512) f32, indices: (32,) int32, out: (1,32,512,512) f32
//
// Round 14: f32 hot pipeline as a MINIMAL delta from the proven round-11
// kernel (same strides, loops, tables, barriers; types f64->f32), plus a
// branch-free flag ballot (3rd bitmap, in d_out) and an atomic-free f64
// fixup kernel (word-owner) replaying the rounds-7-11 f64 value chains.
// Pipeline: canny_fused -> fixup -> hyst_iterate -> mul. d_ws = 2 MB bitmaps.

constexpr int HH = 512;
constexpr int WW = 512;
constexpr int HW = HH * WW;          // 262144 px per channel
constexpr int KCH = 32;              // selected channels
constexpr int WORDS = HW / 32;       // 8192 uint32 words per bitmap per channel

constexpr int TD = 32;               // tile dim
constexpr int NT = HH / TD;          // 16

constexpr int IN_D = 40;             // input tile 40x40 (halo 4)
constexpr int VP_C = 40;             // vp tile 36x40
constexpr int BL_D = 36;             // blur tile 36x36
constexpr int SQ_D = 34;             // mag^2 tile 34x34

// f64 gaussian weights, exact value chain of the reference
constexpr double E2 = 0.13533528323661269189;  // exp(-2.0)
constexpr double E1 = 0.60653065971263342360;  // exp(-0.5)
constexpr double GS = ((((E2 + E1) + 1.0) + E1) + E2);
constexpr double GW0 = E2 / GS, GW1 = E1 / GS, GW2 = 1.0 / GS;

constexpr double T1 = 0.4142135623730950488;   // tan(22.5deg)
constexpr double T2 = 2.4142135623730950488;   // tan(67.5deg)
constexpr double SQ_HI = 0.2 * 0.2;
constexpr double SQ_LO = 0.1 * 0.1;

__device__ __forceinline__ int reflect_idx(int v) {
    return v < 0 ? -v : (v > 511 ? 1022 - v : v);
}
__device__ __forceinline__ int clampi(int v) {
    return v < 0 ? 0 : (v > 511 ? 511 : v);
}

// axis a in {0..3}: NMS neighbor pair, == rint(atan2(gy,gx)*(180/pi)/45) mod 4
__device__ const int AY1[4] = {0, 1, 1, 1};
__device__ const int AX1[4] = {1, 1, 0, -1};

// ---------------- Kernel 1: fused f32 blur + sobel + mag^2 + NMS + flag ballot ----------------
// One 256-thread block per 32x32 tile. LDS (13,504 B):
//   [0, 5760):      vp f32[36*40] -> sq f32[34*34] overlay (vp dead)
//   [5760, 12160):  in f32[40*40] -> bl f32[36*36] overlay (in dead)
//   [12160, 13184): ax u8[32*32] (bit2 = axis-borderline flag)
//   [13184, 13320): RU/RD/CL/CR u8[34] x4
//   [13320, 13480): rmap/cmap u16[40] x2
__global__ __launch_bounds__(256) void canny_fused(const float* __restrict__ x,
                                                   const int* __restrict__ idx,
                                                   unsigned int* __restrict__ weakb,
                                                   unsigned int* __restrict__ strongb,
                                                   unsigned int* __restrict__ flagb) {
    __shared__ __align__(16) char lds[13504];
    float* vp_s = (float*)lds;                             // [36*40]
    float* sq_s = (float*)lds;                             // [34*34] overlay
    float* in_s = (float*)(lds + 5760);                    // [40*40]
    float* bl_s = (float*)(lds + 5760);                    // [36*36] overlay
    unsigned char* ax_s = (unsigned char*)(lds + 12160);   // [32*32]
    unsigned char* RUm = (unsigned char*)(lds + 13184);    // [34]
    unsigned char* RDm = RUm + 34;
    unsigned char* CLm = RUm + 68;
    unsigned char* CRm = RUm + 102;
    unsigned short* rmap = (unsigned short*)(lds + 13320); // [40]
    unsigned short* cmap = rmap + 40;                      // [40]

    int tile = blockIdx.x;
    int k = tile >> 8;                 // 256 tiles per channel
    int t = tile & 255;
    int ty0 = (t >> 4) * TD;
    int tx0 = (t & 15) * TD;
    int tid = threadIdx.x;

    int ch = idx[k];
    const float* img = x + (size_t)ch * HW;

    // ---- index tables (as round 11) ----
    if (tid < 40) {
        rmap[tid] = (unsigned short)reflect_idx(ty0 - 4 + tid);
        cmap[tid] = (unsigned short)reflect_idx(tx0 - 4 + tid);
    } else if (tid >= 64 && tid < 98) {
        int am = tid - 64;
        int u = ty0 - 1 + am;
        RUm[am] = (unsigned char)(clampi(u - 1) - (ty0 - 2));
        RDm[am] = (unsigned char)(clampi(u + 1) - (ty0 - 2));
    } else if (tid >= 128 && tid < 162) {
        int bm = tid - 128;
        int v = tx0 - 1 + bm;
        CLm[bm] = (unsigned char)(clampi(v - 1) - (tx0 - 2));
        CRm[bm] = (unsigned char)(clampi(v + 1) - (tx0 - 2));
    }
    __syncthreads();   // load below consumes rmap/cmap cross-wave (round-10 fix)

    // ---- load input tile 40x40 via reflect maps ----
    {
        int a = tid / 40, b = tid - (tid / 40) * 40;
        while (a < 40) {
            in_s[a * IN_D + b] = img[(int)rmap[a] * WW + (int)cmap[b]];
            b += 16; a += 6;
            if (b >= 40) { b -= 40; a += 1; }
        }
    }
    __syncthreads();

    const float g0 = (float)GW0, g1 = (float)GW1, g2 = (float)GW2;

    // ---- vertical blur (f32): sliding window, lane-major columns ----
    if (tid < 240) {
        int rg = tid / 40;
        int b = tid - 40 * rg;
        int a0 = 6 * rg;
        float w[10];
        #pragma unroll
        for (int j = 0; j < 10; j++) w[j] = in_s[(a0 + j) * IN_D + b];
        #pragma unroll
        for (int i = 0; i < 6; i++) {
            float acc = g0 * w[i];
            acc += g1 * w[i + 1];
            acc += g2 * w[i + 2];
            acc += g1 * w[i + 3];
            acc += g0 * w[i + 4];
            vp_s[(a0 + i) * VP_C + b] = acc;
        }
    }
    __syncthreads();

    // ---- horizontal blur (f32): per-cell linear ----
    {
        int a = tid / 36, b = tid - 36 * (tid / 36);
        while (a < 36) {
            const float* vr = vp_s + a * VP_C + b;
            float acc = g0 * vr[0];
            acc += g1 * vr[1];
            acc += g2 * vr[2];
            acc += g1 * vr[3];
            acc += g0 * vr[4];
            bl_s[a * BL_D + b] = acc;
            b += 4; a += 7;
            if (b >= 36) { b -= 36; a += 1; }
        }
    }
    __syncthreads();   // fences vp reads before sq overlay writes

    // ---- mag^2 + axis (f32), axis-borderline flag in bit 2 ----
    const float T1f = (float)T1, T2f = (float)T2;
    {
        int am = tid / 34, bm = tid - 34 * (tid / 34);
        while (am < 34) {
            int ru = RUm[am], r0 = am + 1, rd = RDm[am];
            int cl = CLm[bm], c0 = bm + 1, cr = CRm[bm];
            float v00 = bl_s[ru * BL_D + cl], v01 = bl_s[ru * BL_D + c0], v02 = bl_s[ru * BL_D + cr];
            float v10 = bl_s[r0 * BL_D + cl],                              v12 = bl_s[r0 * BL_D + cr];
            float v20 = bl_s[rd * BL_D + cl], v21 = bl_s[rd * BL_D + c0], v22 = bl_s[rd * BL_D + cr];
            float gxv = ((((-v00 + v02) + (-2.0f * v10)) + (2.0f * v12)) + (-v20)) + v22;
            float gyv = ((((-v00 + (-2.0f * v01)) + (-v02)) + v20) + (2.0f * v21)) + v22;
            sq_s[am * SQ_D + bm] = (gxv * gxv + gyv * gyv) + 1e-6f;

            float axf = fabsf(gxv), ayf = fabsf(gyv);
            int axis;
            if (ayf < T1f * axf) axis = 0;
            else if (ayf > T2f * axf) axis = 2;
            else {
                float gxf = (gyv < 0.0f) ? -gxv : gxv;
                axis = (gxf > 0.0f) ? 1 : 3;
            }
            float mrg = 3e-4f * (axf + ayf);
            int aflag = ((fabsf(ayf - T1f * axf) <= mrg) |
                         (fabsf(ayf - T2f * axf) <= mrg) |
                         (axf <= mrg) | (ayf <= mrg)) ? 4 : 0;
            if (am >= 1 && am <= TD && bm >= 1 && bm <= TD)
                ax_s[(am - 1) * TD + (bm - 1)] = (unsigned char)(axis | aflag);

            bm += 18; am += 7;
            if (bm >= 34) { bm -= 34; am += 1; }
        }
    }
    __syncthreads();

    // ---- NMS + thresholds (f32) + branch-free flag ballot ----
    #pragma unroll
    for (int q4 = 0; q4 < TD * TD / 256; q4++) {
        int l = q4 * 256 + tid;
        int oy = l >> 5, ox = l & 31;
        int gy = ty0 + oy, gx = tx0 + ox;

        unsigned char av = ax_s[oy * TD + ox];
        int axis = av & 3;
        int dy = AY1[axis], dx = AX1[axis];
        float s = sq_s[(oy + 1) * SQ_D + (ox + 1)];

        int y1 = gy + dy, x1 = gx + dx;
        int y2 = gy - dy, x2 = gx - dx;
        bool in1 = (y1 >= 0) && (y1 < HH) && (x1 >= 0) && (x1 < WW);
        bool in2 = (y2 >= 0) && (y2 < HH) && (x2 >= 0) && (x2 < WW);
        float s1 = in1 ? sq_s[(oy + 1 + dy) * SQ_D + (ox + 1 + dx)] : 0.0f;
        float s2 = in2 ? sq_s[(oy + 1 - dy) * SQ_D + (ox + 1 - dx)] : 0.0f;
        bool keep = (s > s1) && (s > s2);
        bool strong = keep && (s > 0.04f);
        bool weak = keep && (s > 0.01f) && !strong;

        const float e = 3e-4f;
        bool flag = (av & 4) != 0;
        flag = flag | (in1 & (fabsf(s - s1) <= e * (s + s1)));
        flag = flag | (in2 & (fabsf(s - s2) <= e * (s + s2)));
        flag = flag | (fabsf(s - 0.04f) <= e * (s + 0.04f));
        flag = flag | (fabsf(s - 0.01f) <= e * (s + 0.01f));

        unsigned long long wb = __ballot(weak);
        unsigned long long sb = __ballot(strong);
        unsigned long long fb = __ballot(flag);
        if ((tid & 31) == 0) {
            unsigned int ww = (tid & 32) ? (unsigned int)(wb >> 32) : (unsigned int)wb;
            unsigned int sw = (tid & 32) ? (unsigned int)(sb >> 32) : (unsigned int)sb;
            unsigned int fw = (tid & 32) ? (unsigned int)(fb >> 32) : (unsigned int)fb;
            size_t w32 = ((size_t)k * HW + (size_t)gy * WW + tx0) >> 5;
            weakb[w32] = ww;
            strongb[w32] = sw;
            flagb[w32] = fw;
        }
    }
}

// ---------------- Kernel 2: f64 fixup (word-owner, no atomics) ----------------
// Exact rounds-7-11 f64 value chains, reading x directly.
__device__ double blur64g(const float* __restrict__ img, int iy, int ix) {
    const double G[5] = {GW0, GW1, GW2, GW1, GW0};
    double acc = 0.0;
    #pragma unroll
    for (int i = 0; i < 5; i++) {
        double col = 0.0;
        #pragma unroll
        for (int j = 0; j < 5; j++)
            col += G[j] * (double)img[reflect_idx(iy - 2 + j) * WW + reflect_idx(ix - 2 + i)];
        acc += G[i] * col;
    }
    return acc;
}
__device__ void sobel64g(const float* __restrict__ img, int py, int px,
                         double& gxv, double& gyv) {
    int ru = clampi(py - 1), r0 = py, rd = clampi(py + 1);
    int cl = clampi(px - 1), c0 = px, cr = clampi(px + 1);
    double v00 = blur64g(img, ru, cl), v01 = blur64g(img, ru, c0), v02 = blur64g(img, ru, cr);
    double v10 = blur64g(img, r0, cl),                              v12 = blur64g(img, r0, cr);
    double v20 = blur64g(img, rd, cl), v21 = blur64g(img, rd, c0), v22 = blur64g(img, rd, cr);
    gxv = ((((-v00 + v02) + (-2.0 * v10)) + (2.0 * v12)) + (-v20)) + v22;
    gyv = ((((-v00 + (-2.0 * v01)) + (-v02)) + v20) + (2.0 * v21)) + v22;
}

__global__ __launch_bounds__(256) void fixup_kernel(const float* __restrict__ x,
                                                    const int* __restrict__ idx,
                                                    const unsigned int* __restrict__ flagb,
                                                    unsigned int* __restrict__ weakb,
                                                    unsigned int* __restrict__ strongb) {
    unsigned int w = blockIdx.x * 256 + threadIdx.x;   // 0..262143
    unsigned int f = flagb[w];
    if (!f) return;

    int k = (int)(w >> 13);            // 8192 words per channel
    int rem = (int)(w & 8191);
    int gy = rem >> 4;
    int gx0 = (rem & 15) << 5;
    const float* img = x + (size_t)idx[k] * HW;

    unsigned int wk = weakb[w], st = strongb[w];
    while (f) {
        int b = __ffs(f) - 1;
        f &= f - 1;
        int gx = gx0 + b;

        double gxc, gyc;
        sobel64g(img, gy, gx, gxc, gyc);
        double s = (gxc * gxc + gyc * gyc) + 1e-6;

        double ax = fabs(gxc), ay = fabs(gyc);
        int axis;
        if (ay < T1 * ax) axis = 0;
        else if (ay > T2 * ax) axis = 2;
        else {
            double gxf = (gyc < 0.0) ? -gxc : gxc;
            axis = (gxf > 0.0) ? 1 : 3;
        }
        int dy = AY1[axis], dx = AX1[axis];

        double s1 = 0.0, s2 = 0.0, tx, ty;
        int y1 = gy + dy, x1 = gx + dx, y2 = gy - dy, x2 = gx - dx;
        if (y1 >= 0 && y1 < HH && x1 >= 0 && x1 < WW) {
            sobel64g(img, y1, x1, tx, ty);
            s1 = (tx * tx + ty * ty) + 1e-6;
        }
        if (y2 >= 0 && y2 < HH && x2 >= 0 && x2 < WW) {
            sobel64g(img, y2, x2, tx, ty);
            s2 = (tx * tx + ty * ty) + 1e-6;
        }
        bool keep = (s > s1) && (s > s2);
        bool strong = keep && (s > SQ_HI);
        bool weak = keep && (s > SQ_LO) && !strong;

        unsigned int m = 1u << b;
        wk = weak ? (wk | m) : (wk & ~m);
        st = strong ? (st | m) : (st & ~m);
    }
    weakb[w] = wk;
    strongb[w] = st;
}

// ---------------- Kernel 3: hysteresis closure on bitmaps (round 11 verbatim) ----------------
__global__ __launch_bounds__(1024) void hyst_iterate(const unsigned int* __restrict__ weakb,
                                                     unsigned int* __restrict__ strongb) {
    int k = blockIdx.x;
    __shared__ unsigned int Sm[WORDS];
    __shared__ int s_changed;
    int tid = threadIdx.x;

    const unsigned int* wsrc = weakb + (size_t)k * WORDS;
    unsigned int* ssrc = strongb + (size_t)k * WORDS;

    if (tid == 0) s_changed = 0;
    for (int i = tid; i < WORDS; i += 1024) Sm[i] = ssrc[i];
    unsigned int wreg[8];
    #pragma unroll
    for (int q = 0; q < 8; q++) wreg[q] = wsrc[tid * 8 + q];
    __syncthreads();

    for (;;) {
        int loc = 0;
        #pragma unroll
        for (int q = 0; q < 8; q++) {
            int w = tid * 8 + q;
            unsigned int s = Sm[w];
            unsigned int wk = wreg[q] & ~s;
            if (!wk) continue;
            int j = w & 15;
            unsigned int L = j ? Sm[w - 1] : 0u;
            unsigned int R = (j < 15) ? Sm[w + 1] : 0u;
            unsigned int D = (s << 1) | (L >> 31) | (s >> 1) | (R << 31);
            if (w >= 16) {
                unsigned int cu = Sm[w - 16];
                unsigned int Lu = j ? Sm[w - 17] : 0u;
                unsigned int Ru = (j < 15) ? Sm[w - 15] : 0u;
                D |= cu | (cu << 1) | (Lu >> 31) | (cu >> 1) | (Ru << 31);
            }
            if (w < WORDS - 16) {
                unsigned int cd = Sm[w + 16];
                unsigned int Ld = j ? Sm[w + 15] : 0u;
                unsigned int Rd = (j < 15) ? Sm[w + 17] : 0u;
                D |= cd | (cd << 1) | (Ld >> 31) | (cd >> 1) | (Rd << 31);
            }
            unsigned int promoted = wk & D;
            if (promoted) { Sm[w] = s | promoted; loc = 1; }
        }
        if (loc) s_changed = 1;
        __syncthreads();
        int chg = s_changed;
        __syncthreads();
        if (!chg) break;
        if (tid == 0) s_changed = 0;
        __syncthreads();
    }

    for (int i = tid; i < WORDS; i += 1024) ssrc[i] = Sm[i];
}

// ---------------- Kernel 4: out = x[:,indices] * tf, full grid, float4 ----------------
__global__ void mul_kernel(const float* __restrict__ x,
                           const int* __restrict__ idx,
                           const unsigned int* __restrict__ weakb,
                           const unsigned int* __restrict__ strongb,
                           float* __restrict__ out) {
    int gid = blockIdx.x * blockDim.x + threadIdx.x;
    int p = gid * 4;
    if (p >= KCH * HW) return;
    int k = p >> 18;
    int r = p & (HW - 1);
    int ch = idx[k];

    unsigned int sw = strongb[p >> 5];
    unsigned int ww = weakb[p >> 5];
    int b0 = p & 31;

    const float4 xv = *reinterpret_cast<const float4*>(x + (size_t)ch * HW + r);
    float t[4];
    #pragma unroll
    for (int i = 0; i < 4; i++) {
        int b = b0 + i;
        t[i] = ((sw >> b) & 1u) ? 1.0f : (((ww >> b) & 1u) ? 0.5f : 0.0f);
    }
    float4 o;
    o.x = xv.x * t[0];
    o.y = xv.y * t[1];
    o.z = xv.z * t[2];
    o.w = xv.w * t[3];
    *reinterpret_cast<float4*>(out + (size_t)p) = o;
}

extern "C" void kernel_launch(void* const* d_in, const int* in_sizes, int n_in,
                              void* d_out, int out_size, void* d_ws, size_t ws_size,
                              hipStream_t stream) {
    const float* x = (const float*)d_in[0];
    // d_in[1] = params (always 1 here; params==0 changes output shape, impossible
    // given out_size)
    const int* idx = (const int*)d_in[2];
    float* out = (float*)d_out;

    char* ws = (char*)d_ws;
    unsigned int* weakb = (unsigned int*)ws;                 // 1 MB
    unsigned int* strongb = (unsigned int*)(ws + 1048576);   // 1 MB
    // flag bitmap lives in d_out (dead until mul overwrites); fully written
    // by canny_fused every call -> deterministic, no memset needed.
    unsigned int* flagb = (unsigned int*)d_out;              // 1 MB

    int ntiles = KCH * NT * NT;  // 8192
    canny_fused<<<ntiles, 256, 0, stream>>>(x, idx, weakb, strongb, flagb);
    fixup_kernel<<<(KCH * WORDS) / 256, 256, 0, stream>>>(x, idx, flagb, weakb, strongb);
    hyst_iterate<<<KCH, 1024, 0, stream>>>(weakb, strongb);
    mul_kernel<<<(KCH * HW / 4) / 256, 256, 0, stream>>>(x, idx, weakb, strongb, out);
}